// Round 6
// baseline (144.675 us; speedup 1.0000x reference)
//
#include <hip/hip_runtime.h>
#include <hip/hip_bf16.h>

// GPT2 attention. B=2, S=2048, D=1024, H=16, DH=64.
// inputs (f32): x[2,2048,1024], w_attn[1024,3072], b_attn[3072], w_proj[1024,1024], b_proj[1024]
// output (f32): [2,2048,1024]

#define BB 2
#define SS 2048
#define DD 1024
#define HH 16
#define DHH 64
#define MTOK (BB * SS)        // 4096
#define N3D (3 * DD)          // 3072

typedef __attribute__((ext_vector_type(8))) short bf16x8;
typedef __attribute__((ext_vector_type(4))) float f32x4;
typedef __attribute__((ext_vector_type(4))) short short4v;

__device__ __forceinline__ short f2bf(float f) {
  unsigned int x = __float_as_uint(f);
  unsigned int r = (x + 0x7fffu + ((x >> 16) & 1u)) >> 16;
  return (short)r;
}

__device__ __forceinline__ unsigned int cvtpk_bf16(float lo, float hi) {
  unsigned int r;
  asm("v_cvt_pk_bf16_f32 %0, %1, %2" : "=v"(r) : "v"(lo), "v"(hi));
  return r;
}

// ---------------- cast f32 -> bf16 (vectorized x4) ----------------
__global__ void cast_bf16_k(const float* __restrict__ in, short* __restrict__ out, int n4) {
  int i = blockIdx.x * blockDim.x + threadIdx.x;
  if (i < n4) {
    float4 v = reinterpret_cast<const float4*>(in)[i];
    short4v o;
    o[0] = f2bf(v.x); o[1] = f2bf(v.y); o[2] = f2bf(v.z); o[3] = f2bf(v.w);
    reinterpret_cast<short4v*>(out)[i] = o;
  }
}

// ---------------- transpose + cast: W[K][N] f32 -> Wt[N][K] bf16 ----------------
__global__ void transpose_cast_k(const float* __restrict__ W, short* __restrict__ Wt, int K, int N) {
  __shared__ float t[32][33];
  int n0 = blockIdx.x * 32, k0 = blockIdx.y * 32;
  int tx = threadIdx.x, ty = threadIdx.y;
#pragma unroll
  for (int i = 0; i < 4; ++i)
    t[ty + 8 * i][tx] = W[(size_t)(k0 + ty + 8 * i) * N + n0 + tx];
  __syncthreads();
#pragma unroll
  for (int i = 0; i < 4; ++i)
    Wt[(size_t)(n0 + ty + 8 * i) * K + k0 + tx] = f2bf(t[tx][ty + 8 * i]);
}

// ---------------- extract V^T per (b,h): Vt[(b*H+h)*64+d][s] ----------------
__global__ void extract_vt_k(const short* __restrict__ qkv, short* __restrict__ vt) {
  __shared__ short t[32][33];
  int s0 = blockIdx.x * 32, d0 = blockIdx.y * 32;
  int bh = blockIdx.z;
  int b = bh >> 4, h = bh & 15;
  int tx = threadIdx.x, ty = threadIdx.y;
#pragma unroll
  for (int i = 0; i < 4; ++i)
    t[ty + 8 * i][tx] =
        qkv[(size_t)(b * SS + s0 + ty + 8 * i) * N3D + 2 * DD + h * DHH + d0 + tx];
  __syncthreads();
#pragma unroll
  for (int i = 0; i < 4; ++i)
    vt[(size_t)(bh * DHH + d0 + ty + 8 * i) * SS + s0 + tx] = t[tx][ty + 8 * i];
}

// ---------------- GEMM m97-structure: C[M][N] = A[M][K] * Bt[N][K]^T + bias ----------------
// OUTF32=0 additionally pre-scales Q columns (col < DD) by 0.125 for the attention.
template <int OUTF32>
__global__ __launch_bounds__(256) void gemm128_k(const short* __restrict__ A,
                                                 const short* __restrict__ Bt,
                                                 const float* __restrict__ bias,
                                                 void* __restrict__ Cout,
                                                 int M, int N, int K) {
  __shared__ short As[128 * 64];
  __shared__ short Bs[128 * 64];
  int tid = threadIdx.x;
  int m0 = blockIdx.y * 128, n0 = blockIdx.x * 128;
  int w = tid >> 6, lane = tid & 63;
  int wr = w >> 1, wc = w & 1;
  int ln16 = lane & 15, l16 = lane >> 4;

  f32x4 acc[4][4] = {};

  int lrow0 = w * 32 + (lane >> 3);
  int blk_p = lane & 7;

  for (int k0 = 0; k0 < K; k0 += 64) {
#pragma unroll
    for (int i = 0; i < 4; ++i) {
      int row_p = lrow0 + i * 8;
      int colE = ((blk_p ^ (row_p & 7)) << 3);
      __builtin_amdgcn_global_load_lds(
          (const __attribute__((address_space(1))) unsigned int*)&A[(size_t)(m0 + row_p) * K + k0 + colE],
          (__attribute__((address_space(3))) unsigned int*)&As[(w * 4 + i) * 512],
          16, 0, 0);
      __builtin_amdgcn_global_load_lds(
          (const __attribute__((address_space(1))) unsigned int*)&Bt[(size_t)(n0 + row_p) * K + k0 + colE],
          (__attribute__((address_space(3))) unsigned int*)&Bs[(w * 4 + i) * 512],
          16, 0, 0);
    }
    __syncthreads();
#pragma unroll
    for (int kk = 0; kk < 2; ++kk) {
      bf16x8 a[4], bfr[4];
#pragma unroll
      for (int mi = 0; mi < 4; ++mi) {
        int row = wr * 64 + mi * 16 + ln16;
        int blk = (kk * 4 + l16) ^ (row & 7);
        a[mi] = *reinterpret_cast<const bf16x8*>(&As[row * 64 + blk * 8]);
      }
#pragma unroll
      for (int ni = 0; ni < 4; ++ni) {
        int row = wc * 64 + ni * 16 + ln16;
        int blk = (kk * 4 + l16) ^ (row & 7);
        bfr[ni] = *reinterpret_cast<const bf16x8*>(&Bs[row * 64 + blk * 8]);
      }
#pragma unroll
      for (int mi = 0; mi < 4; ++mi)
#pragma unroll
        for (int ni = 0; ni < 4; ++ni)
          acc[mi][ni] = __builtin_amdgcn_mfma_f32_16x16x32_bf16(a[mi], bfr[ni], acc[mi][ni], 0, 0, 0);
    }
    __syncthreads();
  }

#pragma unroll
  for (int mi = 0; mi < 4; ++mi)
#pragma unroll
    for (int ni = 0; ni < 4; ++ni)
#pragma unroll
      for (int ri = 0; ri < 4; ++ri) {
        int row = m0 + wr * 64 + mi * 16 + l16 * 4 + ri;
        int col = n0 + wc * 64 + ni * 16 + ln16;
        float v = acc[mi][ni][ri] + bias[col];
        if (OUTF32) {
          reinterpret_cast<float*>(Cout)[(size_t)row * N + col] = v;
        } else {
          if (col < DD) v *= 0.125f;  // pre-scale Q by 1/sqrt(DH)
          reinterpret_cast<short*>(Cout)[(size_t)row * N + col] = f2bf(v);
        }
      }
}

// ---------------- Flash attention: 8 waves, even/odd KV split, one q-tile per block ----------------
// grid (32, B*H), 512 threads. Waves 0-3 (g=0): even kt; waves 4-7 (g=1): odd kt.
// Wave wq owns q-rows [wq*16, wq*16+16). blockIdx.x descending qt (longest first).
// LDS 49152 B -> 3 blocks/CU (24 waves/CU). K/V unpadded 64x64 tiles, 16B-block XOR
// swizzle (blk ^ row&7) write+read -- the gemm128 pattern that measures 0 conflicts.
#define MASKV -3.0e38f
__global__ __launch_bounds__(512) void flash_attn_k(const short* __restrict__ qkv,
                                                    const short* __restrict__ vt,
                                                    short* __restrict__ ctx) {
  __shared__ __align__(16) char smem[49152];
  // shorts: Ks [0,8192) = 2 par x 64r x 64c ; Vs [8192,16384) ; Ps [16384,24576)
  // combine aliases: Od f32 at bytes [0,16640), mls f32 at bytes [17408,17920).
  short* Sm = reinterpret_cast<short*>(smem);
  float* Od = reinterpret_cast<float*>(smem);
  float* mls = reinterpret_cast<float*>(smem + 17408);

  int tid = threadIdx.x;
  int qt = 31 - blockIdx.x;  // longest blocks dispatched first
  int bh = blockIdx.y;
  int b = bh >> 4, h = bh & 15;
  int q0 = qt * 64;
  int wg = tid >> 6, lane = tid & 63;
  int g = wg >> 2, wq = wg & 3;
  int ln16 = lane & 15, l16 = lane >> 4;
  int t8 = tid & 255;
  int tb = tid >> 8;  // staging parity buffer this thread fills
  int r0 = t8 >> 3, cb = t8 & 7;
  // store indices (shorts); (r0+32)&7 == r0&7 so same XOR for both rows
  int ksw = tb * 4096 + r0 * 64 + ((cb ^ (r0 & 7)) << 3);
  int psq = 16384 + (wg << 10) + (ln16 << 6);  // Ps base for this wave+q

  const short* kbase = qkv + (size_t)(b * SS) * N3D + DD + h * DHH;  // + s*N3D + d
  const short* vbase = vt + (size_t)(bh * DHH) * SS;                 // + d*SS + s

  // Q fragments in registers (Q pre-scaled by 0.125 in the QKV GEMM epilogue)
  bf16x8 qf[2];
  {
    const short* qrow = qkv + (size_t)(b * SS + q0 + wq * 16 + ln16) * N3D + h * DHH;
    qf[0] = *reinterpret_cast<const bf16x8*>(qrow + l16 * 8);
    qf[1] = *reinterpret_cast<const bf16x8*>(qrow + 32 + l16 * 8);
  }
  float m_ = -1e30f, l_ = 0.f;
  f32x4 cacc[4] = {};

  int ns = (qt + 2) >> 1;
  uint4 kr0, kr1, vr0, vr1;
  {
    int kt_s = tb <= qt ? tb : qt;
    kr0 = *reinterpret_cast<const uint4*>(kbase + (size_t)(kt_s * 64 + r0) * N3D + cb * 8);
    kr1 = *reinterpret_cast<const uint4*>(kbase + (size_t)(kt_s * 64 + r0 + 32) * N3D + cb * 8);
    vr0 = *reinterpret_cast<const uint4*>(vbase + (size_t)r0 * SS + kt_s * 64 + cb * 8);
    vr1 = *reinterpret_cast<const uint4*>(vbase + (size_t)(r0 + 32) * SS + kt_s * 64 + cb * 8);
  }

#pragma unroll 1
  for (int s = 0; s < ns; ++s) {
    *reinterpret_cast<uint4*>(&Sm[ksw]) = kr0;
    *reinterpret_cast<uint4*>(&Sm[ksw + 2048]) = kr1;
    *reinterpret_cast<uint4*>(&Sm[8192 + ksw]) = vr0;
    *reinterpret_cast<uint4*>(&Sm[8192 + ksw + 2048]) = vr1;
    __syncthreads();

    // prefetch next super-iter (clamped; latency hides under softmax+PV)
    {
      int kt_n = 2 * (s + 1) + tb;
      if (kt_n > qt) kt_n = qt;
      kr0 = *reinterpret_cast<const uint4*>(kbase + (size_t)(kt_n * 64 + r0) * N3D + cb * 8);
      kr1 = *reinterpret_cast<const uint4*>(kbase + (size_t)(kt_n * 64 + r0 + 32) * N3D + cb * 8);
      vr0 = *reinterpret_cast<const uint4*>(vbase + (size_t)r0 * SS + kt_n * 64 + cb * 8);
      vr1 = *reinterpret_cast<const uint4*>(vbase + (size_t)(r0 + 32) * SS + kt_n * 64 + cb * 8);
    }

    int kt_c = 2 * s + g;
    if (kt_c <= qt) {
      // QK^T swapped: sacc[ni][ri] = S^T[k = ni*16+l16*4+ri][q = ln16]
      f32x4 sacc[4] = {};
#pragma unroll
      for (int kk = 0; kk < 2; ++kk)
#pragma unroll
        for (int ni = 0; ni < 4; ++ni) {
          int row = ni * 16 + ln16;
          bf16x8 kf = *reinterpret_cast<const bf16x8*>(
              &Sm[g * 4096 + row * 64 + (((kk * 4 + l16) ^ (row & 7)) << 3)]);
          sacc[ni] = __builtin_amdgcn_mfma_f32_16x16x32_bf16(kf, qf[kk], sacc[ni], 0, 0, 0);
        }

      float p[4][4];
      float mx = MASKV;
      if (kt_c == qt) {  // diagonal tile: causal mask
        int qg = q0 + wq * 16 + ln16;
#pragma unroll
        for (int ni = 0; ni < 4; ++ni)
#pragma unroll
          for (int ri = 0; ri < 4; ++ri) {
            int kg = kt_c * 64 + ni * 16 + l16 * 4 + ri;
            float v = (kg > qg) ? MASKV : sacc[ni][ri];
            p[ni][ri] = v;
            mx = fmaxf(mx, v);
          }
      } else {
#pragma unroll
        for (int ni = 0; ni < 4; ++ni)
#pragma unroll
          for (int ri = 0; ri < 4; ++ri) {
            p[ni][ri] = sacc[ni][ri];
            mx = fmaxf(mx, sacc[ni][ri]);
          }
      }
      mx = fmaxf(mx, __shfl_xor(mx, 16));
      mx = fmaxf(mx, __shfl_xor(mx, 32));

      // defer-max (T13): only rescale when max grew by > 8
      int keep = __all(mx <= m_ + 8.0f);
      float mn = m_;
      if (!keep) {
        mn = fmaxf(m_, mx);
        float sc = __expf(m_ - mn);
        l_ *= sc;
        float scr[4];
#pragma unroll
        for (int ri = 0; ri < 4; ++ri) scr[ri] = __shfl(sc, l16 * 4 + ri);
#pragma unroll
        for (int di = 0; di < 4; ++di)
#pragma unroll
          for (int ri = 0; ri < 4; ++ri) cacc[di][ri] *= scr[ri];
        m_ = mn;
      }

      float sum = 0.f;
#pragma unroll
      for (int ni = 0; ni < 4; ++ni)
#pragma unroll
        for (int ri = 0; ri < 4; ++ri) {
          float e = __expf(p[ni][ri] - mn);
          p[ni][ri] = e;
          sum += e;
        }
      sum += __shfl_xor(sum, 16);
      sum += __shfl_xor(sum, 32);
      l_ += sum;

      // pack P -> Ps[wave][q=ln16][k], XOR-swizzled 16B blocks (blk ^= q&7)
#pragma unroll
      for (int ni = 0; ni < 4; ++ni) {
        uint2 u;
        u.x = cvtpk_bf16(p[ni][0], p[ni][1]);
        u.y = cvtpk_bf16(p[ni][2], p[ni][3]);
        int idx = psq + ((((ni << 1) + (l16 >> 1)) ^ (ln16 & 7)) << 3) + ((l16 & 1) << 2);
        *reinterpret_cast<uint2*>(&Sm[idx]) = u;
      }
      asm volatile("s_waitcnt lgkmcnt(0)" ::: "memory");

      // ctx += P @ V
#pragma unroll
      for (int kk = 0; kk < 2; ++kk) {
        bf16x8 pa = *reinterpret_cast<const bf16x8*>(
            &Sm[psq + ((((kk << 2) + l16) ^ (ln16 & 7)) << 3)]);
#pragma unroll
        for (int di = 0; di < 4; ++di) {
          int row = di * 16 + ln16;
          bf16x8 vb = *reinterpret_cast<const bf16x8*>(
              &Sm[8192 + g * 4096 + row * 64 + (((kk * 4 + l16) ^ (row & 7)) << 3)]);
          cacc[di] = __builtin_amdgcn_mfma_f32_16x16x32_bf16(pa, vb, cacc[di], 0, 0, 0);
        }
      }
    }
    __syncthreads();
  }

  // ---- combine even/odd partials (aliases K/V region; all kv reads done) ----
  if (g == 1) {
    if (l16 == 0) { mls[wq * 16 + ln16] = m_; mls[64 + wq * 16 + ln16] = l_; }
#pragma unroll
    for (int di = 0; di < 4; ++di)
#pragma unroll
      for (int ri = 0; ri < 4; ++ri)
        Od[wq * 1040 + (l16 * 4 + ri) * 65 + di * 16 + ln16] = cacc[di][ri];
  }
  __syncthreads();
  if (g == 0) {
    float m1 = mls[wq * 16 + ln16], l1 = mls[64 + wq * 16 + ln16];
    float mM = fmaxf(m_, m1);
    float e0 = __expf(m_ - mM), e1 = __expf(m1 - mM);
    float inv = 1.f / (l_ * e0 + l1 * e1);
    float e0r[4], e1r[4], ivr[4];
#pragma unroll
    for (int ri = 0; ri < 4; ++ri) {
      int src = l16 * 4 + ri;
      e0r[ri] = __shfl(e0, src);
      e1r[ri] = __shfl(e1, src);
      ivr[ri] = __shfl(inv, src);
    }
#pragma unroll
    for (int di = 0; di < 4; ++di)
#pragma unroll
      for (int ri = 0; ri < 4; ++ri) {
        float a1 = Od[wq * 1040 + (l16 * 4 + ri) * 65 + di * 16 + ln16];
        float o = (cacc[di][ri] * e0r[ri] + a1 * e1r[ri]) * ivr[ri];
        int row = q0 + wq * 16 + l16 * 4 + ri;
        int col = h * DHH + di * 16 + ln16;
        ctx[(size_t)(b * SS + row) * DD + col] = f2bf(o);
      }
  }
}

extern "C" void kernel_launch(void* const* d_in, const int* in_sizes, int n_in,
                              void* d_out, int out_size, void* d_ws, size_t ws_size,
                              hipStream_t stream) {
  const float* x      = (const float*)d_in[0];
  const float* w_attn = (const float*)d_in[1];
  const float* b_attn = (const float*)d_in[2];
  const float* w_proj = (const float*)d_in[3];
  const float* b_proj = (const float*)d_in[4];
  float* out = (float*)d_out;

  char* ws = (char*)d_ws;
  short* xb     = (short*)(ws);                       // 8388608 B
  short* wattnT = (short*)(ws + 8388608);             // 6291456 B
  short* wprojT = (short*)(ws + 14680064);            // 2097152 B
  short* qkv    = (short*)(ws + 16777216);            // 25165824 B
  short* vt     = (short*)(ws + 41943040);            // 8388608 B
  short* ctx    = (short*)(ws + 50331648);            // 8388608 B

  {
    int n4 = (MTOK * DD) / 4;
    cast_bf16_k<<<(n4 + 255) / 256, 256, 0, stream>>>(x, xb, n4);
  }
  transpose_cast_k<<<dim3(N3D / 32, DD / 32), dim3(32, 8), 0, stream>>>(w_attn, wattnT, DD, N3D);
  transpose_cast_k<<<dim3(DD / 32, DD / 32), dim3(32, 8), 0, stream>>>(w_proj, wprojT, DD, DD);
  gemm128_k<0><<<dim3(N3D / 128, MTOK / 128), 256, 0, stream>>>(xb, wattnT, b_attn, qkv, MTOK, N3D, DD);
  extract_vt_k<<<dim3(SS / 32, DHH / 32, BB * HH), dim3(32, 8), 0, stream>>>(qkv, vt);
  flash_attn_k<<<dim3(32, BB * HH), 512, 0, stream>>>(qkv, vt, ctx);
  gemm128_k<1><<<dim3(DD / 128, MTOK / 128), 256, 0, stream>>>(ctx, wprojT, b_proj, out, MTOK, DD, DD);
}

// Round 7
// 132.628 us; speedup vs baseline: 1.0908x; 1.0908x over previous
//
#include <hip/hip_runtime.h>
#include <hip/hip_bf16.h>

// GPT2 attention. B=2, S=2048, D=1024, H=16, DH=64.
// inputs (f32): x[2,2048,1024], w_attn[1024,3072], b_attn[3072], w_proj[1024,1024], b_proj[1024]
// output (f32): [2,2048,1024]

#define BB 2
#define SS 2048
#define DD 1024
#define HH 16
#define DHH 64
#define MTOK (BB * SS)        // 4096
#define N3D (3 * DD)          // 3072

typedef __attribute__((ext_vector_type(8))) short bf16x8;
typedef __attribute__((ext_vector_type(4))) float f32x4;
typedef __attribute__((ext_vector_type(4))) short short4v;

__device__ __forceinline__ short f2bf(float f) {
  unsigned int x = __float_as_uint(f);
  unsigned int r = (x + 0x7fffu + ((x >> 16) & 1u)) >> 16;
  return (short)r;
}

__device__ __forceinline__ unsigned int cvtpk_bf16(float lo, float hi) {
  unsigned int r;
  asm("v_cvt_pk_bf16_f32 %0, %1, %2" : "=v"(r) : "v"(lo), "v"(hi));
  return r;
}

// ---------------- cast f32 -> bf16 (vectorized x4) ----------------
__global__ void cast_bf16_k(const float* __restrict__ in, short* __restrict__ out, int n4) {
  int i = blockIdx.x * blockDim.x + threadIdx.x;
  if (i < n4) {
    float4 v = reinterpret_cast<const float4*>(in)[i];
    short4v o;
    o[0] = f2bf(v.x); o[1] = f2bf(v.y); o[2] = f2bf(v.z); o[3] = f2bf(v.w);
    reinterpret_cast<short4v*>(out)[i] = o;
  }
}

// ---------------- transpose + cast: W[K][N] f32 -> Wt[N][K] bf16 ----------------
__global__ void transpose_cast_k(const float* __restrict__ W, short* __restrict__ Wt, int K, int N) {
  __shared__ float t[32][33];
  int n0 = blockIdx.x * 32, k0 = blockIdx.y * 32;
  int tx = threadIdx.x, ty = threadIdx.y;
#pragma unroll
  for (int i = 0; i < 4; ++i)
    t[ty + 8 * i][tx] = W[(size_t)(k0 + ty + 8 * i) * N + n0 + tx];
  __syncthreads();
#pragma unroll
  for (int i = 0; i < 4; ++i)
    Wt[(size_t)(n0 + ty + 8 * i) * K + k0 + tx] = f2bf(t[tx][ty + 8 * i]);
}

// ---------------- extract V^T per (b,h): Vt[(b*H+h)*64+d][s] ----------------
__global__ void extract_vt_k(const short* __restrict__ qkv, short* __restrict__ vt) {
  __shared__ short t[32][33];
  int s0 = blockIdx.x * 32, d0 = blockIdx.y * 32;
  int bh = blockIdx.z;
  int b = bh >> 4, h = bh & 15;
  int tx = threadIdx.x, ty = threadIdx.y;
#pragma unroll
  for (int i = 0; i < 4; ++i)
    t[ty + 8 * i][tx] =
        qkv[(size_t)(b * SS + s0 + ty + 8 * i) * N3D + 2 * DD + h * DHH + d0 + tx];
  __syncthreads();
#pragma unroll
  for (int i = 0; i < 4; ++i)
    vt[(size_t)(bh * DHH + d0 + ty + 8 * i) * SS + s0 + tx] = t[tx][ty + 8 * i];
}

// ---------------- GEMM m97-structure: C[M][N] = A[M][K] * Bt[N][K]^T + bias ----------------
// OUTF32=0 additionally pre-scales Q columns (col < DD) by 0.125 for the attention.
template <int OUTF32>
__global__ __launch_bounds__(256) void gemm128_k(const short* __restrict__ A,
                                                 const short* __restrict__ Bt,
                                                 const float* __restrict__ bias,
                                                 void* __restrict__ Cout,
                                                 int M, int N, int K) {
  __shared__ short As[128 * 64];
  __shared__ short Bs[128 * 64];
  int tid = threadIdx.x;
  int m0 = blockIdx.y * 128, n0 = blockIdx.x * 128;
  int w = tid >> 6, lane = tid & 63;
  int wr = w >> 1, wc = w & 1;
  int ln16 = lane & 15, l16 = lane >> 4;

  f32x4 acc[4][4] = {};

  int lrow0 = w * 32 + (lane >> 3);
  int blk_p = lane & 7;

  for (int k0 = 0; k0 < K; k0 += 64) {
#pragma unroll
    for (int i = 0; i < 4; ++i) {
      int row_p = lrow0 + i * 8;
      int colE = ((blk_p ^ (row_p & 7)) << 3);
      __builtin_amdgcn_global_load_lds(
          (const __attribute__((address_space(1))) unsigned int*)&A[(size_t)(m0 + row_p) * K + k0 + colE],
          (__attribute__((address_space(3))) unsigned int*)&As[(w * 4 + i) * 512],
          16, 0, 0);
      __builtin_amdgcn_global_load_lds(
          (const __attribute__((address_space(1))) unsigned int*)&Bt[(size_t)(n0 + row_p) * K + k0 + colE],
          (__attribute__((address_space(3))) unsigned int*)&Bs[(w * 4 + i) * 512],
          16, 0, 0);
    }
    __syncthreads();
#pragma unroll
    for (int kk = 0; kk < 2; ++kk) {
      bf16x8 a[4], bfr[4];
#pragma unroll
      for (int mi = 0; mi < 4; ++mi) {
        int row = wr * 64 + mi * 16 + ln16;
        int blk = (kk * 4 + l16) ^ (row & 7);
        a[mi] = *reinterpret_cast<const bf16x8*>(&As[row * 64 + blk * 8]);
      }
#pragma unroll
      for (int ni = 0; ni < 4; ++ni) {
        int row = wc * 64 + ni * 16 + ln16;
        int blk = (kk * 4 + l16) ^ (row & 7);
        bfr[ni] = *reinterpret_cast<const bf16x8*>(&Bs[row * 64 + blk * 8]);
      }
#pragma unroll
      for (int mi = 0; mi < 4; ++mi)
#pragma unroll
        for (int ni = 0; ni < 4; ++ni)
          acc[mi][ni] = __builtin_amdgcn_mfma_f32_16x16x32_bf16(a[mi], bfr[ni], acc[mi][ni], 0, 0, 0);
    }
    __syncthreads();
  }

#pragma unroll
  for (int mi = 0; mi < 4; ++mi)
#pragma unroll
    for (int ni = 0; ni < 4; ++ni)
#pragma unroll
      for (int ri = 0; ri < 4; ++ri) {
        int row = m0 + wr * 64 + mi * 16 + l16 * 4 + ri;
        int col = n0 + wc * 64 + ni * 16 + ln16;
        float v = acc[mi][ni][ri] + bias[col];
        if (OUTF32) {
          reinterpret_cast<float*>(Cout)[(size_t)row * N + col] = v;
        } else {
          if (col < DD) v *= 0.125f;  // pre-scale Q by 1/sqrt(DH)
          reinterpret_cast<short*>(Cout)[(size_t)row * N + col] = f2bf(v);
        }
      }
}

// ---------------- Flash attention: shared-KV dual-q sweep, dbuf staging, 1 barrier/iter ----------------
// grid (16, B*H), 512 threads, 8 waves. Block handles q-tiles qtA=31-pj AND qtB=pj in ONE
// kv sweep over kt<=qtA (B's range is a subset). Wave wg: parity g=wg>>2 (kt%2==g),
// q-sub wq=wg&3 (rows wq*16..+16 of each 64-row tile). K/V double-buffered (one barrier/iter).
// LDS 81920 B = 2 blocks/CU; uniform work (33 tile-units/block).
#define MASKV -3.0e38f
__global__ __launch_bounds__(512) void flash_attn_k(const short* __restrict__ qkv,
                                                    const short* __restrict__ vt,
                                                    short* __restrict__ ctx) {
  __shared__ __align__(16) char smem[81920];
  // shorts: K[buf d][par g] at d*8192+g*4096, [0,16384) ; V at 16384+d*8192+g*4096,
  // [16384,32768) ; Ps at 32768+wg*1024, [32768,40960). Combine aliases (post-loop):
  // OdA bytes [0,16640), OdB [16640,33280), mls [33280,34304).
  short* Sm = reinterpret_cast<short*>(smem);
  float* OdA = reinterpret_cast<float*>(smem);
  float* OdB = reinterpret_cast<float*>(smem + 16640);
  float* mls = reinterpret_cast<float*>(smem + 33280);

  int tid = threadIdx.x;
  int pj = blockIdx.x;  // 0..15
  int bh = blockIdx.y;
  int b = bh >> 4, h = bh & 15;
  int qtA = 31 - pj, qtB = pj;
  int q0A = qtA * 64, q0B = qtB * 64;
  int wg = tid >> 6, lane = tid & 63;
  int g = wg >> 2, wq = wg & 3;
  int ln16 = lane & 15, l16 = lane >> 4;
  int t8 = tid & 255;
  int tb = tid >> 8;  // staging parity (== g)
  int r0 = t8 >> 3, cb = t8 & 7;
  int kswz = r0 * 64 + ((cb ^ (r0 & 7)) << 3);  // swizzled store idx within a 64x64 tile
  int psq = 32768 + (wg << 10) + (ln16 << 6);   // Ps base for this wave+q

  const short* kbase = qkv + (size_t)(b * SS) * N3D + DD + h * DHH;  // + s*N3D + d
  const short* vbase = vt + (size_t)(bh * DHH) * SS;                 // + d*SS + s

  // Q fragments for both tiles (Q pre-scaled by 0.125 in the QKV GEMM epilogue)
  bf16x8 qfA[2], qfB[2];
  {
    const short* qa = qkv + (size_t)(b * SS + q0A + wq * 16 + ln16) * N3D + h * DHH;
    qfA[0] = *reinterpret_cast<const bf16x8*>(qa + l16 * 8);
    qfA[1] = *reinterpret_cast<const bf16x8*>(qa + 32 + l16 * 8);
    const short* qb = qkv + (size_t)(b * SS + q0B + wq * 16 + ln16) * N3D + h * DHH;
    qfB[0] = *reinterpret_cast<const bf16x8*>(qb + l16 * 8);
    qfB[1] = *reinterpret_cast<const bf16x8*>(qb + 32 + l16 * 8);
  }
  float mA = -1e30f, lA = 0.f, mB = -1e30f, lB = 0.f;
  f32x4 caccA[4] = {}, caccB[4] = {};

  int ns = (33 - pj) >> 1;  // iters; kt pair {2s, 2s+1}, range 0..qtA

  // one tile-step: QK^T (swapped) -> online softmax -> PV, updating (m,l,cacc)
  auto step = [&](f32x4 (&cacc)[4], bf16x8 (&qf)[2], float& m_, float& l_,
                  bool diag, int qg, int kt_c, int kb, int vbb) {
    f32x4 sacc[4] = {};
    __builtin_amdgcn_s_setprio(1);
#pragma unroll
    for (int kk = 0; kk < 2; ++kk)
#pragma unroll
      for (int ni = 0; ni < 4; ++ni) {
        int row = ni * 16 + ln16;
        bf16x8 kf = *reinterpret_cast<const bf16x8*>(
            &Sm[kb + row * 64 + (((kk * 4 + l16) ^ (row & 7)) << 3)]);
        sacc[ni] = __builtin_amdgcn_mfma_f32_16x16x32_bf16(kf, qf[kk], sacc[ni], 0, 0, 0);
      }
    __builtin_amdgcn_s_setprio(0);

    float p[4][4];
    float mx = MASKV;
    if (diag) {
#pragma unroll
      for (int ni = 0; ni < 4; ++ni)
#pragma unroll
        for (int ri = 0; ri < 4; ++ri) {
          int kg = kt_c * 64 + ni * 16 + l16 * 4 + ri;
          float v = (kg > qg) ? MASKV : sacc[ni][ri];
          p[ni][ri] = v;
          mx = fmaxf(mx, v);
        }
    } else {
#pragma unroll
      for (int ni = 0; ni < 4; ++ni)
#pragma unroll
        for (int ri = 0; ri < 4; ++ri) {
          p[ni][ri] = sacc[ni][ri];
          mx = fmaxf(mx, sacc[ni][ri]);
        }
    }
    mx = fmaxf(mx, __shfl_xor(mx, 16));
    mx = fmaxf(mx, __shfl_xor(mx, 32));

    int keep = __all(mx <= m_ + 8.0f);  // defer-max (T13)
    float mn = m_;
    if (!keep) {
      mn = fmaxf(m_, mx);
      float sc = __expf(m_ - mn);
      l_ *= sc;
      float scr[4];
#pragma unroll
      for (int ri = 0; ri < 4; ++ri) scr[ri] = __shfl(sc, l16 * 4 + ri);
#pragma unroll
      for (int di = 0; di < 4; ++di)
#pragma unroll
        for (int ri = 0; ri < 4; ++ri) cacc[di][ri] *= scr[ri];
      m_ = mn;
    }

    float sum = 0.f;
#pragma unroll
    for (int ni = 0; ni < 4; ++ni)
#pragma unroll
      for (int ri = 0; ri < 4; ++ri) {
        float e = __expf(p[ni][ri] - mn);
        p[ni][ri] = e;
        sum += e;
      }
    sum += __shfl_xor(sum, 16);
    sum += __shfl_xor(sum, 32);
    l_ += sum;

    // pack P -> Ps (XOR-swizzled 16B blocks, blk ^= q&7)
#pragma unroll
    for (int ni = 0; ni < 4; ++ni) {
      uint2 u;
      u.x = cvtpk_bf16(p[ni][0], p[ni][1]);
      u.y = cvtpk_bf16(p[ni][2], p[ni][3]);
      int idx = psq + ((((ni << 1) + (l16 >> 1)) ^ (ln16 & 7)) << 3) + ((l16 & 1) << 2);
      *reinterpret_cast<uint2*>(&Sm[idx]) = u;
    }
    asm volatile("s_waitcnt lgkmcnt(0)" ::: "memory");

    __builtin_amdgcn_s_setprio(1);
#pragma unroll
    for (int kk = 0; kk < 2; ++kk) {
      bf16x8 pa = *reinterpret_cast<const bf16x8*>(
          &Sm[psq + ((((kk << 2) + l16) ^ (ln16 & 7)) << 3)]);
#pragma unroll
      for (int di = 0; di < 4; ++di) {
        int row = di * 16 + ln16;
        bf16x8 vb = *reinterpret_cast<const bf16x8*>(
            &Sm[vbb + row * 64 + (((kk * 4 + l16) ^ (row & 7)) << 3)]);
        cacc[di] = __builtin_amdgcn_mfma_f32_16x16x32_bf16(pa, vb, cacc[di], 0, 0, 0);
      }
    }
    __builtin_amdgcn_s_setprio(0);
  };

  // prologue: tile pair 0 -> buf0; load pair 1 into regs
  uint4 kr0, kr1, vr0, vr1;
  {
    int kt0 = tb;  // <= qtA always (qtA >= 16)
    kr0 = *reinterpret_cast<const uint4*>(kbase + (size_t)(kt0 * 64 + r0) * N3D + cb * 8);
    kr1 = *reinterpret_cast<const uint4*>(kbase + (size_t)(kt0 * 64 + r0 + 32) * N3D + cb * 8);
    vr0 = *reinterpret_cast<const uint4*>(vbase + (size_t)r0 * SS + kt0 * 64 + cb * 8);
    vr1 = *reinterpret_cast<const uint4*>(vbase + (size_t)(r0 + 32) * SS + kt0 * 64 + cb * 8);
    *reinterpret_cast<uint4*>(&Sm[tb * 4096 + kswz]) = kr0;
    *reinterpret_cast<uint4*>(&Sm[tb * 4096 + kswz + 2048]) = kr1;
    *reinterpret_cast<uint4*>(&Sm[16384 + tb * 4096 + kswz]) = vr0;
    *reinterpret_cast<uint4*>(&Sm[16384 + tb * 4096 + kswz + 2048]) = vr1;
    int kt1 = 2 + tb;
    if (kt1 > qtA) kt1 = qtA;
    kr0 = *reinterpret_cast<const uint4*>(kbase + (size_t)(kt1 * 64 + r0) * N3D + cb * 8);
    kr1 = *reinterpret_cast<const uint4*>(kbase + (size_t)(kt1 * 64 + r0 + 32) * N3D + cb * 8);
    vr0 = *reinterpret_cast<const uint4*>(vbase + (size_t)r0 * SS + kt1 * 64 + cb * 8);
    vr1 = *reinterpret_cast<const uint4*>(vbase + (size_t)(r0 + 32) * SS + kt1 * 64 + cb * 8);
  }
  __syncthreads();

#pragma unroll 1
  for (int s = 0; s < ns; ++s) {
    int d = s & 1;
    if (s + 1 < ns) {  // regs hold tile pair s+1 -> write to other buffer
      int dn = d ^ 1;
      *reinterpret_cast<uint4*>(&Sm[dn * 8192 + tb * 4096 + kswz]) = kr0;
      *reinterpret_cast<uint4*>(&Sm[dn * 8192 + tb * 4096 + kswz + 2048]) = kr1;
      *reinterpret_cast<uint4*>(&Sm[16384 + dn * 8192 + tb * 4096 + kswz]) = vr0;
      *reinterpret_cast<uint4*>(&Sm[16384 + dn * 8192 + tb * 4096 + kswz + 2048]) = vr1;
    }

    int kt_c = 2 * s + g;
    if (kt_c <= qtA) {
      int kb = d * 8192 + g * 4096;
      int vbb = 16384 + d * 8192 + g * 4096;
      step(caccA, qfA, mA, lA, kt_c == qtA, q0A + wq * 16 + ln16, kt_c, kb, vbb);
      if (kt_c <= qtB)
        step(caccB, qfB, mB, lB, kt_c == qtB, q0B + wq * 16 + ln16, kt_c, kb, vbb);
    }

    if (s + 2 < ns) {  // issue loads for tile pair s+2
      int kt_n = 2 * (s + 2) + tb;
      if (kt_n > qtA) kt_n = qtA;
      kr0 = *reinterpret_cast<const uint4*>(kbase + (size_t)(kt_n * 64 + r0) * N3D + cb * 8);
      kr1 = *reinterpret_cast<const uint4*>(kbase + (size_t)(kt_n * 64 + r0 + 32) * N3D + cb * 8);
      vr0 = *reinterpret_cast<const uint4*>(vbase + (size_t)r0 * SS + kt_n * 64 + cb * 8);
      vr1 = *reinterpret_cast<const uint4*>(vbase + (size_t)(r0 + 32) * SS + kt_n * 64 + cb * 8);
    }
    __syncthreads();
  }

  // ---- combine even/odd partials for both tiles (aliases K/V region; loop done) ----
  if (g == 1) {
    if (l16 == 0) {
      mls[wq * 16 + ln16] = mA;
      mls[64 + wq * 16 + ln16] = lA;
      mls[128 + wq * 16 + ln16] = mB;
      mls[192 + wq * 16 + ln16] = lB;
    }
#pragma unroll
    for (int di = 0; di < 4; ++di)
#pragma unroll
      for (int ri = 0; ri < 4; ++ri) {
        OdA[wq * 1040 + (l16 * 4 + ri) * 65 + di * 16 + ln16] = caccA[di][ri];
        OdB[wq * 1040 + (l16 * 4 + ri) * 65 + di * 16 + ln16] = caccB[di][ri];
      }
  }
  __syncthreads();
  if (g == 0) {
#pragma unroll
    for (int t = 0; t < 2; ++t) {
      float* Od = t ? OdB : OdA;
      f32x4* cacc = t ? caccB : caccA;
      float m_ = t ? mB : mA, l_ = t ? lB : lA;
      int q0 = t ? q0B : q0A;
      float m1 = mls[t * 128 + wq * 16 + ln16], l1 = mls[t * 128 + 64 + wq * 16 + ln16];
      float mM = fmaxf(m_, m1);
      float e0 = __expf(m_ - mM), e1 = __expf(m1 - mM);
      float inv = 1.f / (l_ * e0 + l1 * e1);
      float e0r[4], e1r[4], ivr[4];
#pragma unroll
      for (int ri = 0; ri < 4; ++ri) {
        int src = l16 * 4 + ri;
        e0r[ri] = __shfl(e0, src);
        e1r[ri] = __shfl(e1, src);
        ivr[ri] = __shfl(inv, src);
      }
#pragma unroll
      for (int di = 0; di < 4; ++di)
#pragma unroll
        for (int ri = 0; ri < 4; ++ri) {
          float a1 = Od[wq * 1040 + (l16 * 4 + ri) * 65 + di * 16 + ln16];
          float o = (cacc[di][ri] * e0r[ri] + a1 * e1r[ri]) * ivr[ri];
          int row = q0 + wq * 16 + l16 * 4 + ri;
          int col = h * DHH + di * 16 + ln16;
          ctx[(size_t)(b * SS + row) * DD + col] = f2bf(o);
        }
    }
  }
}

extern "C" void kernel_launch(void* const* d_in, const int* in_sizes, int n_in,
                              void* d_out, int out_size, void* d_ws, size_t ws_size,
                              hipStream_t stream) {
  const float* x      = (const float*)d_in[0];
  const float* w_attn = (const float*)d_in[1];
  const float* b_attn = (const float*)d_in[2];
  const float* w_proj = (const float*)d_in[3];
  const float* b_proj = (const float*)d_in[4];
  float* out = (float*)d_out;

  char* ws = (char*)d_ws;
  short* xb     = (short*)(ws);                       // 8388608 B
  short* wattnT = (short*)(ws + 8388608);             // 6291456 B
  short* wprojT = (short*)(ws + 14680064);            // 2097152 B
  short* qkv    = (short*)(ws + 16777216);            // 25165824 B
  short* vt     = (short*)(ws + 41943040);            // 8388608 B
  short* ctx    = (short*)(ws + 50331648);            // 8388608 B

  {
    int n4 = (MTOK * DD) / 4;
    cast_bf16_k<<<(n4 + 255) / 256, 256, 0, stream>>>(x, xb, n4);
  }
  transpose_cast_k<<<dim3(N3D / 32, DD / 32), dim3(32, 8), 0, stream>>>(w_attn, wattnT, DD, N3D);
  transpose_cast_k<<<dim3(DD / 32, DD / 32), dim3(32, 8), 0, stream>>>(w_proj, wprojT, DD, DD);
  gemm128_k<0><<<dim3(N3D / 128, MTOK / 128), 256, 0, stream>>>(xb, wattnT, b_attn, qkv, MTOK, N3D, DD);
  extract_vt_k<<<dim3(SS / 32, DHH / 32, BB * HH), dim3(32, 8), 0, stream>>>(qkv, vt);
  flash_attn_k<<<dim3(16, BB * HH), 512, 0, stream>>>(qkv, vt, ctx);
  gemm128_k<1><<<dim3(DD / 128, MTOK / 128), 256, 0, stream>>>(ctx, wprojT, b_proj, out, MTOK, DD, DD);
}